// Round 7
// baseline (122.002 us; speedup 1.0000x reference)
//
#include <hip/hip_runtime.h>
#include <hip/hip_bf16.h>

typedef short bf16x8 __attribute__((ext_vector_type(8)));
typedef float f32x4  __attribute__((ext_vector_type(4)));

#define BLOCK 256
#define NCOL  16              // batch columns per block
#define ROWS  96              // 80 A-rows + 4 pbc rows + 12 pad
#define NCH   14              // chunks of 32 s = 128 real-k = 4 ksteps(32)
#define KS1   56              // f1 k-steps total (K=1792)
#define KS2   6               // f2 k-steps (K=192)
#define FSTR  272             // F col stride: 68 dw == 4 mod 32, 16B-aligned
#define EFSTR 544             // Ef col stride (spans FB0+FB1)

#define ESH_OFF 0             // ushort4 [41][16] = 5248
#define FB0_OFF 5248          // 16*272 = 4352
#define FB1_OFF 9600          // 16*272 = 4352
#define BMF_OFF 13952         // f32 [80][16] = 5120
#define LDS_BYTES 19072
#define ASH_OFF 0             // f32 [96][16] = 6144, alias post-loop

__device__ __forceinline__ unsigned short f2bf(float f) {
    union { float f; unsigned u; } v; v.f = f;
    unsigned r = v.u + 0x7FFFu + ((v.u >> 16) & 1u);
    return (unsigned short)(r >> 16);
}
__device__ __forceinline__ float bfl(unsigned u) {
    union { unsigned q; float f; } v; v.q = u << 16; return v.f;
}
__device__ __forceinline__ float bfh(unsigned u) {
    union { unsigned q; float f; } v; v.q = u & 0xffff0000u; return v.f;
}
__device__ __forceinline__ unsigned pk2(float a, float b) {
    __hip_bfloat162 h = __float22bfloat162_rn(make_float2(a, b));
    unsigned u; __builtin_memcpy(&u, &h, 4); return u;
}

// prep: Wp [ks][96 rows][32 k] (A-frag-contiguous), W2p likewise, meta int2.
// Row encoding r = o*4 + p*2 + (re/im); rows 80-83 = pbc C rows; rest zero.
// k within step: t=k&3 -> (c=t>>1 re/im of F, i=t&1 pol); W-plane j = i^p.
__global__ void prep_kernel(const float* __restrict__ W1,
                            const float* __restrict__ W2,
                            const float* __restrict__ pbcC,
                            const int* __restrict__ m_idx,
                            const int* __restrict__ n_idx,
                            unsigned short* __restrict__ Wp,
                            unsigned short* __restrict__ W2p,
                            int2* __restrict__ meta, int S) {
    int idx = blockIdx.x * 256 + threadIdx.x;
    const int N1 = KS1 * ROWS * 8, N2 = KS2 * ROWS * 8;
    if (idx < N1) {
        int ks = idx / (ROWS * 8), rem = idx - ks * (ROWS * 8);
        int row = rem >> 3, kq = rem & 7;
        int s = ks * 8 + kq;
        float2 wj0 = make_float2(0.f, 0.f), wj1 = make_float2(0.f, 0.f);
        int p = 0, r = 0;
        if (s < S) {
            if (row < 80) {
                int o = row >> 2; p = (row >> 1) & 1; r = row & 1;
                wj0 = ((const float2*)W1)[(size_t)(o * 2 + 0) * S + s];
                wj1 = ((const float2*)W1)[(size_t)(o * 2 + 1) * S + s];
            } else if (row < 84) {
                p = (row >> 1) & 1; r = row & 1;
                wj0 = ((const float2*)pbcC)[s];   // only i==p (j==0) contributes
            }
        }
        ushort4 h;
        unsigned short us[4];
#pragma unroll
        for (int t = 0; t < 4; ++t) {
            int i = t & 1, cc = t >> 1, j = i ^ p;
            float2 w = j ? wj1 : wj0;
            float v = (cc == 0) ? (r ? w.y : w.x) : (r ? w.x : -w.y);
            us[t] = f2bf(v);
        }
        h.x = us[0]; h.y = us[1]; h.z = us[2]; h.w = us[3];
        ((ushort4*)Wp)[(size_t)(ks * ROWS + row) * 8 + kq] = h;
        return;
    }
    idx -= N1;
    if (idx < N2) {
        int ks = idx / (ROWS * 8), rem = idx - ks * (ROWS * 8);
        int row = rem >> 3, kq = rem & 7;
        int m = ks * 8 + kq;
        float2 wj0 = make_float2(0.f, 0.f), wj1 = make_float2(0.f, 0.f);
        int p = 0, r = 0;
        if (m < 41 && row < 80) {
            int o = row >> 2; p = (row >> 1) & 1; r = row & 1;
            wj0 = ((const float2*)W2)[(o * 2 + 0) * 41 + m];
            wj1 = ((const float2*)W2)[(o * 2 + 1) * 41 + m];
        }
        ushort4 h;
        unsigned short us[4];
#pragma unroll
        for (int t = 0; t < 4; ++t) {
            int i = t & 1, cc = t >> 1, j = i ^ p;
            float2 w = j ? wj1 : wj0;
            float v = (cc == 0) ? (r ? w.y : w.x) : (r ? w.x : -w.y);
            us[t] = f2bf(v);
        }
        h.x = us[0]; h.y = us[1]; h.z = us[2]; h.w = us[3];
        ((ushort4*)W2p)[(size_t)(ks * ROWS + row) * 8 + kq] = h;
        return;
    }
    idx -= N2;
    if (idx < S) meta[idx] = make_int2(m_idx[idx], n_idx[idx]);
}

__global__ __launch_bounds__(BLOCK, 4) void eqsonn_kernel(
    const float* __restrict__ x,            // [B,41,2,2]
    const float* __restrict__ task,         // [B,4]
    const unsigned short* __restrict__ Wp,  // [56][96][32] bf16
    const unsigned short* __restrict__ W2p, // [6][96][32] bf16
    const int2* __restrict__ meta,          // [S] {m,n}
    const float* __restrict__ b1,           // [10,2]
    const float* __restrict__ b2,           // [10,2]
    float* __restrict__ out,                // [B,2,2]
    int B, int S)
{
    __shared__ alignas(16) char ldsb[LDS_BYTES];
    const int tid  = threadIdx.x;
    const int lane = tid & 63;
    const int wave = tid >> 6;
    const int col  = lane & 15;   // A-row / B-col lane index
    const int quad = lane >> 4;   // k-eighth / s-subgroup
    const int b0   = blockIdx.x * NCOL;
    const int wu   = __builtin_amdgcn_readfirstlane(wave);
    const bool dual = (wu < 2);
    const int  mtA  = dual ? wu * 2 : wu + 2;   // tiles {0,1},{2,3},{4},{5}

    // ---- stage E bf16 [k][col] ----
    for (int e = tid; e < 41 * NCOL; e += BLOCK) {
        int bb = e / 41, k = e - bb * 41;
        int bs = b0 + bb; if (bs > B - 1) bs = B - 1;
        float4 v = ((const float4*)x)[(size_t)bs * 41 + k];
        ushort4 h;
        h.x = f2bf(v.x); h.y = f2bf(v.y); h.z = f2bf(v.z); h.w = f2bf(v.w);
        ((ushort4*)(ldsb + ESH_OFF))[k * NCOL + bb] = h;
    }
    __syncthreads();

    // ---- produce Ef (48 slots x 4 k) into FB0+FB1 at EFSTR ----
#pragma unroll
    for (int j = 0; j < 3; ++j) {
        int sl = wu * 12 + j * 4 + quad;
        uint2 h = make_uint2(0u, 0u);
        if (sl < 41) {
            uint2 ue = *(const uint2*)(ldsb + ESH_OFF + (sl * NCOL + col) * 8);
            h.x = (ue.x & 0xffffu) | (ue.y << 16);       // [ReE0, ReE1]
            h.y = (ue.x >> 16) | (ue.y & 0xffff0000u);   // [ImE0, ImE1]
        }
        *(uint2*)(ldsb + FB0_OFF + col * EFSTR + sl * 8) = h;
    }
    __syncthreads();

    // ---- f2 GEMM (tile 5 is all-zero padding: wave 3 skips) ----
    if (wu != 3) {
        f32x4 fa0 = {0.f,0.f,0.f,0.f}, fa1 = {0.f,0.f,0.f,0.f};
        const unsigned short* a2 = W2p + (mtA * 16 + col) * 32 + quad * 8;
#pragma unroll
        for (int ks = 0; ks < KS2; ++ks) {
            bf16x8 bfr = *(const bf16x8*)(ldsb + FB0_OFF + col * EFSTR + ks * 64 + quad * 16);
            bf16x8 a0 = *(const bf16x8*)(a2 + (size_t)ks * 3072);
            fa0 = __builtin_amdgcn_mfma_f32_16x16x32_bf16(a0, bfr, fa0, 0, 0, 0);
            if (dual) {
                bf16x8 a1 = *(const bf16x8*)(a2 + (size_t)ks * 3072 + 512);
                fa1 = __builtin_amdgcn_mfma_f32_16x16x32_bf16(a1, bfr, fa1, 0, 0, 0);
            }
        }
        float* BMf = (float*)(ldsb + BMF_OFF);
#pragma unroll
        for (int reg = 0; reg < 4; ++reg) {
            int row = mtA * 16 + quad * 4 + reg;    // C/D: row=quad*4+reg, col=lane&15
            BMf[row * NCOL + col] = fa0[reg];
            if (dual) BMf[(row + 16) * NCOL + col] = fa1[reg];
        }
    }
    __syncthreads();   // Ef consumed -> FB free for f1 chunks

    // ---- producer: 2 (col,s) pairs per lane per chunk ----
    auto produce = [&](int chbase, int bufoff) {
#pragma unroll
        for (int j = 0; j < 2; ++j) {
            int sl = wu * 8 + j * 4 + quad;
            int s  = chbase + sl;
            uint2 h = make_uint2(0u, 0u);
            if (s < S) {
                int2 mm = meta[s];
                int m = mm.x, n = mm.y;
                uint2 um = *(const uint2*)(ldsb + ESH_OFF + ((20 + m) * NCOL + col) * 8);
                uint2 ub = *(const uint2*)(ldsb + ESH_OFF + ((20 + m + n) * NCOL + col) * 8);
                uint2 un = *(const uint2*)(ldsb + ESH_OFF + ((20 + n) * NCOL + col) * 8);
                float Emx = bfl(um.x), Emy = bfh(um.x), Emz = bfl(um.y), Emw = bfh(um.y);
                float Ebx = bfl(ub.x), Eby = bfh(ub.x), Ebz = bfl(ub.y), Ebw = bfh(ub.y);
                float Enx = bfl(un.x), Eny = bfh(un.x), Enz = bfl(un.y), Enw = bfh(un.y);
                float sr = Emx * Ebx + Emy * Eby + Emz * Ebz + Emw * Ebw;
                float si = Emy * Ebx - Emx * Eby + Emw * Ebz - Emz * Ebw;
                float F0r = sr * Enx - si * Eny, F0i = sr * Eny + si * Enx;
                float F1r = sr * Enz - si * Enw, F1i = sr * Enw + si * Enz;
                h.x = pk2(F0r, F1r); h.y = pk2(F0i, F1i);
            }
            *(uint2*)(ldsb + bufoff + col * FSTR + sl * 8) = h;
        }
    };

    produce(0, FB0_OFF);
    __syncthreads();

    // ---- main loop: one barrier per 32-s chunk, double-buffered F ----
    f32x4 acc0 = {0.f,0.f,0.f,0.f}, acc1 = {0.f,0.f,0.f,0.f};
    const unsigned short* aBase = Wp + (mtA * 16 + col) * 32 + quad * 8;
    for (int ch = 0; ch < NCH; ++ch) {
        const int rbuf = (ch & 1) ? FB1_OFF : FB0_OFF;
        const int wbuf = (ch & 1) ? FB0_OFF : FB1_OFF;
        if (ch + 1 < NCH) produce((ch + 1) * 32, wbuf);
        {
            const unsigned short* ap = aBase + (size_t)(ch * 4) * 3072;
#pragma unroll
            for (int j = 0; j < 4; ++j) {
                bf16x8 bfr = *(const bf16x8*)(ldsb + rbuf + col * FSTR + j * 64 + quad * 16);
                bf16x8 a0 = *(const bf16x8*)(ap + (size_t)j * 3072);
                acc0 = __builtin_amdgcn_mfma_f32_16x16x32_bf16(a0, bfr, acc0, 0, 0, 0);
                if (dual) {
                    bf16x8 a1 = *(const bf16x8*)(ap + (size_t)j * 3072 + 512);
                    acc1 = __builtin_amdgcn_mfma_f32_16x16x32_bf16(a1, bfr, acc1, 0, 0, 0);
                }
            }
        }
        __syncthreads();
    }

    // ---- stage A partials f32 (alias over Esh/FB0; Esh dead) ----
    float* Ashf = (float*)(ldsb + ASH_OFF);
#pragma unroll
    for (int reg = 0; reg < 4; ++reg) {
        int row = mtA * 16 + quad * 4 + reg;
        Ashf[row * NCOL + col] = acc0[reg];
        if (dual) Ashf[(row + 16) * NCOL + col] = acc1[reg];
    }
    __syncthreads();

    // ---- epilogue: wave 0 lanes 0..15 ----
    if (wave == 0 && lane < NCOL) {
        const float* BMf = (const float*)(ldsb + BMF_OFF);
        int c = lane;
        float pr0 = Ashf[80 * NCOL + c], pi0 = Ashf[81 * NCOL + c];
        float pr1 = Ashf[82 * NCOL + c], pi1 = Ashf[83 * NCOL + c];
        float t0 = 0.f, t1 = 0.f, t2 = 0.f, t3 = 0.f;
#pragma unroll
        for (int o = 0; o < 10; ++o) {
            float b2r = b2[o * 2], b2i = b2[o * 2 + 1];
            float b1r = b1[o * 2], b1i = b1[o * 2 + 1];
            int rb = o * 4;
            float B0r = BMf[(rb + 0) * NCOL + c] + b2r;
            float B0i = BMf[(rb + 1) * NCOL + c] + b2i;
            float B1r = BMf[(rb + 2) * NCOL + c] + b2r;
            float B1i = BMf[(rb + 3) * NCOL + c] + b2i;
            float A0r = Ashf[(rb + 0) * NCOL + c] + b1r;
            float A0i = Ashf[(rb + 1) * NCOL + c] + b1i;
            float A1r = Ashf[(rb + 2) * NCOL + c] + b1r;
            float A1i = Ashf[(rb + 3) * NCOL + c] + b1i;
            // A*B*conj(B) + conj(A)*B*B = 2*Re(A*conj(B)) * B
            float g0 = 2.f * (A0r * B0r + A0i * B0i);
            t0 += g0 * B0r; t1 += g0 * B0i;
            float g1 = 2.f * (A1r * B1r + A1i * B1i);
            t2 += g1 * B1r; t3 += g1 * B1i;
        }
        int b = b0 + c;
        if (b < B) {
            float dbm = task[(size_t)b * 4];
            float P   = exp2f(dbm * 0.33219280948873623f) * 0.5f;  // 10^(dbm/10)/2
            float kP2 = 3.1622776601683794e-05f * P * P;           // 1e-4/sqrt(10)*P^2
            float4 Ec = ((const float4*)x)[(size_t)b * 41 + 20];   // fp32 center symbol
            float4 o4;
            o4.x = Ec.x + P * pr0 + kP2 * t0;
            o4.y = Ec.y + P * pi0 + kP2 * t1;
            o4.z = Ec.z + P * pr1 + kP2 * t2;
            o4.w = Ec.w + P * pi1 + kP2 * t3;
            ((float4*)out)[b] = o4;
        }
    }
}

extern "C" void kernel_launch(void* const* d_in, const int* in_sizes, int n_in,
                              void* d_out, int out_size, void* d_ws, size_t ws_size,
                              hipStream_t stream) {
    const float* x     = (const float*)d_in[0];
    const float* task  = (const float*)d_in[1];
    const float* pbcC  = (const float*)d_in[2];
    const float* W1    = (const float*)d_in[3];
    const float* b1    = (const float*)d_in[4];
    const float* W2    = (const float*)d_in[5];
    const float* b2    = (const float*)d_in[6];
    const int*   m_idx = (const int*)d_in[7];
    const int*   n_idx = (const int*)d_in[8];
    float* out = (float*)d_out;

    int S = in_sizes[7];
    int B = in_sizes[0] / (41 * 2 * 2);

    unsigned short* Wp  = (unsigned short*)d_ws;                      // 56*96*32*2 = 344064
    unsigned short* W2p = (unsigned short*)((char*)d_ws + 344064);    // 6*96*32*2  = 36864
    int2*           met = (int2*)((char*)d_ws + 344064 + 36864);      // S*8

    int prep_n = KS1 * ROWS * 8 + KS2 * ROWS * 8 + S;
    prep_kernel<<<(prep_n + 255) / 256, 256, 0, stream>>>(
        W1, W2, pbcC, m_idx, n_idx, Wp, W2p, met, S);

    int grid = (B + NCOL - 1) / NCOL;
    eqsonn_kernel<<<grid, BLOCK, 0, stream>>>(x, task, Wp, W2p, met, b1, b2,
                                              out, B, S);
}

// Round 8
// 121.468 us; speedup vs baseline: 1.0044x; 1.0044x over previous
//
#include <hip/hip_runtime.h>
#include <hip/hip_bf16.h>

typedef short bf16x8 __attribute__((ext_vector_type(8)));
typedef float f32x4  __attribute__((ext_vector_type(4)));

#define ROWS  96              // prep row stride (80 used + 4 pbc + pad)
#define KS1   56              // f1 k-steps (K=1792, 8 s per ks)
#define KS2   6               // f2 k-steps (K=192, 8 m per ks)
#define KST   62              // total ks slots in F buffer

#define WP_OFF   0            // ushort [56][96][32] = 344064 B
#define W2P_OFF  344064       // ushort [6][96][32]  = 36864 B
#define META_OFF 380928       // int2 [S]
#define F_OFF    384512       // uint4 [62*4][nb]  (3968 B per batch)

__device__ __forceinline__ unsigned short f2bf(float f) {
    union { float f; unsigned u; } v; v.f = f;
    unsigned r = v.u + 0x7FFFu + ((v.u >> 16) & 1u);
    return (unsigned short)(r >> 16);
}
__device__ __forceinline__ float bf2f(unsigned short h) {
    union { unsigned u; float f; } v; v.u = ((unsigned)h) << 16;
    return v.f;
}
__device__ __forceinline__ unsigned pk2(float a, float b) {
    __hip_bfloat162 h = __float22bfloat162_rn(make_float2(a, b));
    unsigned u; __builtin_memcpy(&u, &h, 4); return u;
}
__device__ __forceinline__ bf16x8 asbf(uint4 v) {
    union { uint4 u; bf16x8 b; } z; z.u = v; return z.b;
}

// prep (layouts validated in r7): Wp [ks][96][32], W2p [ks2][96][32], meta int2.
// Row r = o*4 + p*2 + (re/im); rows 80-83 of Wp = pbc C rows.
// k in step: t=k&3 -> (c=t>>1 re/im, i=t&1 pol); plane j = i^p.
__global__ void prep_kernel(const float* __restrict__ W1,
                            const float* __restrict__ W2,
                            const float* __restrict__ pbcC,
                            const int* __restrict__ m_idx,
                            const int* __restrict__ n_idx,
                            unsigned short* __restrict__ Wp,
                            unsigned short* __restrict__ W2p,
                            int2* __restrict__ meta, int S) {
    int idx = blockIdx.x * 256 + threadIdx.x;
    const int N1 = KS1 * ROWS * 8, N2 = KS2 * ROWS * 8;
    if (idx < N1) {
        int ks = idx / (ROWS * 8), rem = idx - ks * (ROWS * 8);
        int row = rem >> 3, kq = rem & 7;
        int s = ks * 8 + kq;
        float2 wj0 = make_float2(0.f, 0.f), wj1 = make_float2(0.f, 0.f);
        int p = 0, r = 0;
        if (s < S) {
            if (row < 80) {
                int o = row >> 2; p = (row >> 1) & 1; r = row & 1;
                wj0 = ((const float2*)W1)[(size_t)(o * 2 + 0) * S + s];
                wj1 = ((const float2*)W1)[(size_t)(o * 2 + 1) * S + s];
            } else if (row < 84) {
                p = (row >> 1) & 1; r = row & 1;
                wj0 = ((const float2*)pbcC)[s];
            }
        }
        ushort4 h; unsigned short us[4];
#pragma unroll
        for (int t = 0; t < 4; ++t) {
            int i = t & 1, cc = t >> 1, j = i ^ p;
            float2 w = j ? wj1 : wj0;
            float v = (cc == 0) ? (r ? w.y : w.x) : (r ? w.x : -w.y);
            us[t] = f2bf(v);
        }
        h.x = us[0]; h.y = us[1]; h.z = us[2]; h.w = us[3];
        ((ushort4*)Wp)[(size_t)(ks * ROWS + row) * 8 + kq] = h;
        return;
    }
    idx -= N1;
    if (idx < N2) {
        int ks = idx / (ROWS * 8), rem = idx - ks * (ROWS * 8);
        int row = rem >> 3, kq = rem & 7;
        int m = ks * 8 + kq;
        float2 wj0 = make_float2(0.f, 0.f), wj1 = make_float2(0.f, 0.f);
        int p = 0, r = 0;
        if (m < 41 && row < 80) {
            int o = row >> 2; p = (row >> 1) & 1; r = row & 1;
            wj0 = ((const float2*)W2)[(o * 2 + 0) * 41 + m];
            wj1 = ((const float2*)W2)[(o * 2 + 1) * 41 + m];
        }
        ushort4 h; unsigned short us[4];
#pragma unroll
        for (int t = 0; t < 4; ++t) {
            int i = t & 1, cc = t >> 1, j = i ^ p;
            float2 w = j ? wj1 : wj0;
            float v = (cc == 0) ? (r ? w.y : w.x) : (r ? w.x : -w.y);
            us[t] = f2bf(v);
        }
        h.x = us[0]; h.y = us[1]; h.z = us[2]; h.w = us[3];
        ((ushort4*)W2p)[(size_t)(ks * ROWS + row) * 8 + kq] = h;
        return;
    }
    idx -= N2;
    if (idx < S) meta[idx] = make_int2(m_idx[idx], n_idx[idx]);
}

// Kernel A: triplet features -> F[(ks*4+q)*nbg + b_local] uint4 (bf16x8).
// k' = kq*4 + t, s = ks*8+kq, t order [F0r,F1r,F0i,F1i]. ks 56..61 = Ef.
// Barrier-free after E staging: wave w owns ks = h*28 + w*7 .. +6.
__global__ __launch_bounds__(256, 4) void feat_kernel(
    const float* __restrict__ x, const int2* __restrict__ meta,
    uint4* __restrict__ Fbuf, int B, int S, int b_start, int nbg)
{
    __shared__ ushort4 Esh[41 * 64];
    const int tid = threadIdx.x, lane = tid & 63;
    const int wu = __builtin_amdgcn_readfirstlane(tid >> 6);
    const int bg = blockIdx.x >> 1, h = blockIdx.x & 1;
    const int c = lane;
    const int bl0 = bg * 64;

    for (int e = tid; e < 41 * 64; e += 256) {
        int bb = e / 41, k = e - bb * 41;
        int bs = b_start + bl0 + bb; if (bs > B - 1) bs = B - 1;
        float4 v = ((const float4*)x)[(size_t)bs * 41 + k];
        ushort4 hh;
        hh.x = f2bf(v.x); hh.y = f2bf(v.y); hh.z = f2bf(v.z); hh.w = f2bf(v.w);
        Esh[k * 64 + bb] = hh;
    }
    __syncthreads();

    const int bl = bl0 + c;
    for (int t7 = 0; t7 < 7; ++t7) {
        int ks = h * 28 + wu * 7 + t7;
        unsigned v[16];
#pragma unroll
        for (int kq = 0; kq < 8; ++kq) {
            int s = ks * 8 + kq;
            unsigned lo = 0u, hi = 0u;
            if (s < S) {
                int2 mm = meta[s];                  // wave-uniform s_load
                ushort4 um = Esh[(20 + mm.x) * 64 + c];
                ushort4 ub = Esh[(20 + mm.x + mm.y) * 64 + c];
                ushort4 un = Esh[(20 + mm.y) * 64 + c];
                float Emx = bf2f(um.x), Emy = bf2f(um.y), Emz = bf2f(um.z), Emw = bf2f(um.w);
                float Ebx = bf2f(ub.x), Eby = bf2f(ub.y), Ebz = bf2f(ub.z), Ebw = bf2f(ub.w);
                float Enx = bf2f(un.x), Eny = bf2f(un.y), Enz = bf2f(un.z), Enw = bf2f(un.w);
                float sr = Emx * Ebx + Emy * Eby + Emz * Ebz + Emw * Ebw;
                float si = Emy * Ebx - Emx * Eby + Emw * Ebz - Emz * Ebw;
                float F0r = sr * Enx - si * Eny, F0i = sr * Eny + si * Enx;
                float F1r = sr * Enz - si * Enw, F1i = sr * Enw + si * Enz;
                lo = pk2(F0r, F1r); hi = pk2(F0i, F1i);
            }
            v[kq * 2] = lo; v[kq * 2 + 1] = hi;
        }
#pragma unroll
        for (int q = 0; q < 4; ++q)
            Fbuf[(ks * 4 + q) * nbg + bl] =
                make_uint4(v[q * 4], v[q * 4 + 1], v[q * 4 + 2], v[q * 4 + 3]);
    }
    if (h == 0) {   // Ef: ks2 = wu, and wu+4 for waves 0,1
#pragma unroll
        for (int rep = 0; rep < 2; ++rep) {
            int ks2 = wu + rep * 4;
            if (ks2 <= 5) {
                unsigned v[16];
#pragma unroll
                for (int mq = 0; mq < 8; ++mq) {
                    int m = ks2 * 8 + mq;
                    unsigned lo = 0u, hi = 0u;
                    if (m < 41) {
                        ushort4 e = Esh[m * 64 + c];
                        lo = (unsigned)e.x | ((unsigned)e.z << 16);  // [ReE0,ReE1]
                        hi = (unsigned)e.y | ((unsigned)e.w << 16);  // [ImE0,ImE1]
                    }
                    v[mq * 2] = lo; v[mq * 2 + 1] = hi;
                }
#pragma unroll
                for (int q = 0; q < 4; ++q)
                    Fbuf[((56 + ks2) * 4 + q) * nbg + bl] =
                        make_uint4(v[q * 4], v[q * 4 + 1], v[q * 4 + 2], v[q * 4 + 3]);
            }
        }
    }
}

// Kernel B: barrier-free K-loop GEMM + fused epilogue.
// Block: N=32 cols, 4 waves = 2 ntiles x 2 K-halves. Wave owns all M-tiles
// for its ntile (F-frag loaded once, 6/5 MFMAs on it).
__global__ __launch_bounds__(256, 4) void gemm_kernel(
    const float* __restrict__ x, const float* __restrict__ task,
    const unsigned short* __restrict__ Wp, const unsigned short* __restrict__ W2p,
    const uint4* __restrict__ Fbuf,
    const float* __restrict__ b1, const float* __restrict__ b2,
    float* __restrict__ out, int B, int b_start, int nbg)
{
    __shared__ float Sum[176 * 32];   // rows 0..95 f1(+pbc), 96..175 f2
    const int tid = threadIdx.x, lane = tid & 63, wave = tid >> 6;
    const int l15 = lane & 15, quad = lane >> 4;
    const int nt = wave & 1, kh = wave >> 1;
    const int c0 = blockIdx.x * 32;
    const int colb = c0 + nt * 16 + l15;

    f32x4 a1[6], a2[5];
#pragma unroll
    for (int i = 0; i < 6; ++i) a1[i] = (f32x4){0.f, 0.f, 0.f, 0.f};
#pragma unroll
    for (int i = 0; i < 5; ++i) a2[i] = (f32x4){0.f, 0.f, 0.f, 0.f};

    const unsigned short* apb = Wp + l15 * 32 + quad * 8;
#pragma unroll 2
    for (int ks = kh * 28; ks < kh * 28 + 28; ++ks) {
        bf16x8 bfr = asbf(Fbuf[(ks * 4 + quad) * nbg + colb]);
        const unsigned short* ap = apb + ks * (96 * 32);
#pragma unroll
        for (int mt = 0; mt < 6; ++mt)
            a1[mt] = __builtin_amdgcn_mfma_f32_16x16x32_bf16(
                *(const bf16x8*)(ap + mt * 512), bfr, a1[mt], 0, 0, 0);
    }
    const unsigned short* ap2b = W2p + l15 * 32 + quad * 8;
#pragma unroll
    for (int t = 0; t < 3; ++t) {
        int k2 = kh * 3 + t;
        bf16x8 bfr = asbf(Fbuf[((56 + k2) * 4 + quad) * nbg + colb]);
        const unsigned short* ap = ap2b + k2 * (96 * 32);
#pragma unroll
        for (int mt = 0; mt < 5; ++mt)
            a2[mt] = __builtin_amdgcn_mfma_f32_16x16x32_bf16(
                *(const bf16x8*)(ap + mt * 512), bfr, a2[mt], 0, 0, 0);
    }

    const int cc = nt * 16 + l15;
    if (kh == 1) {
#pragma unroll
        for (int mt = 0; mt < 6; ++mt)
#pragma unroll
            for (int reg = 0; reg < 4; ++reg)
                Sum[(mt * 16 + quad * 4 + reg) * 32 + cc] = a1[mt][reg];
#pragma unroll
        for (int mt = 0; mt < 5; ++mt)
#pragma unroll
            for (int reg = 0; reg < 4; ++reg)
                Sum[(96 + mt * 16 + quad * 4 + reg) * 32 + cc] = a2[mt][reg];
    }
    __syncthreads();
    if (kh == 0) {
#pragma unroll
        for (int mt = 0; mt < 6; ++mt)
#pragma unroll
            for (int reg = 0; reg < 4; ++reg)
                Sum[(mt * 16 + quad * 4 + reg) * 32 + cc] += a1[mt][reg];
#pragma unroll
        for (int mt = 0; mt < 5; ++mt)
#pragma unroll
            for (int reg = 0; reg < 4; ++reg)
                Sum[(96 + mt * 16 + quad * 4 + reg) * 32 + cc] += a2[mt][reg];
    }
    __syncthreads();

    if (wave == 0 && lane < 32) {
        int col = lane;
        float pr0 = Sum[80 * 32 + col], pi0 = Sum[81 * 32 + col];
        float pr1 = Sum[82 * 32 + col], pi1 = Sum[83 * 32 + col];
        float t0 = 0.f, t1 = 0.f, t2 = 0.f, t3 = 0.f;
#pragma unroll
        for (int o = 0; o < 10; ++o) {
            float b2r = b2[o * 2], b2i = b2[o * 2 + 1];
            float b1r = b1[o * 2], b1i = b1[o * 2 + 1];
            int rb = o * 4;
            float B0r = Sum[(96 + rb + 0) * 32 + col] + b2r;
            float B0i = Sum[(96 + rb + 1) * 32 + col] + b2i;
            float B1r = Sum[(96 + rb + 2) * 32 + col] + b2r;
            float B1i = Sum[(96 + rb + 3) * 32 + col] + b2i;
            float A0r = Sum[(rb + 0) * 32 + col] + b1r;
            float A0i = Sum[(rb + 1) * 32 + col] + b1i;
            float A1r = Sum[(rb + 2) * 32 + col] + b1r;
            float A1i = Sum[(rb + 3) * 32 + col] + b1i;
            // A*B*conj(B) + conj(A)*B*B = 2*Re(A*conj(B)) * B
            float g0 = 2.f * (A0r * B0r + A0i * B0i);
            t0 += g0 * B0r; t1 += g0 * B0i;
            float g1 = 2.f * (A1r * B1r + A1i * B1i);
            t2 += g1 * B1r; t3 += g1 * B1i;
        }
        int b = b_start + c0 + col;
        if (b < B) {
            float dbm = task[(size_t)b * 4];
            float P   = exp2f(dbm * 0.33219280948873623f) * 0.5f;  // 10^(dbm/10)/2
            float kP2 = 3.1622776601683794e-05f * P * P;           // 1e-4/sqrt(10)*P^2
            float4 Ec = ((const float4*)x)[(size_t)b * 41 + 20];
            float4 o4;
            o4.x = Ec.x + P * pr0 + kP2 * t0;
            o4.y = Ec.y + P * pi0 + kP2 * t1;
            o4.z = Ec.z + P * pr1 + kP2 * t2;
            o4.w = Ec.w + P * pi1 + kP2 * t3;
            ((float4*)out)[b] = o4;
        }
    }
}

extern "C" void kernel_launch(void* const* d_in, const int* in_sizes, int n_in,
                              void* d_out, int out_size, void* d_ws, size_t ws_size,
                              hipStream_t stream) {
    const float* x     = (const float*)d_in[0];
    const float* task  = (const float*)d_in[1];
    const float* pbcC  = (const float*)d_in[2];
    const float* W1    = (const float*)d_in[3];
    const float* b1    = (const float*)d_in[4];
    const float* W2    = (const float*)d_in[5];
    const float* b2    = (const float*)d_in[6];
    const int*   m_idx = (const int*)d_in[7];
    const int*   n_idx = (const int*)d_in[8];
    float* out = (float*)d_out;

    int S = in_sizes[7];
    int B = in_sizes[0] / (41 * 2 * 2);

    char* ws = (char*)d_ws;
    unsigned short* Wp  = (unsigned short*)(ws + WP_OFF);
    unsigned short* W2p = (unsigned short*)(ws + W2P_OFF);
    int2*           met = (int2*)(ws + META_OFF);
    uint4*          Fb  = (uint4*)(ws + F_OFF);

    int prep_n = KS1 * ROWS * 8 + KS2 * ROWS * 8 + S;
    prep_kernel<<<(prep_n + 255) / 256, 256, 0, stream>>>(
        W1, W2, pbcC, m_idx, n_idx, Wp, W2p, met, S);

    // F needs 3968 B per batch; group over batch if workspace is smaller.
    long avail = (long)ws_size - F_OFF;
    int nb = B, ngroups = 1;
    if (avail < 3968L * (long)B) {
        long nbmax = avail / 3968L; nbmax = (nbmax / 64) * 64;
        if (nbmax < 64) nbmax = 64;
        ngroups = (int)(((long)B + nbmax - 1) / nbmax);
        nb = (int)((((B + ngroups - 1) / ngroups) + 63) & ~63);
    }
    for (int g = 0; g < ngroups; ++g) {
        int bs = g * nb;
        int nbg = B - bs;
        if (nbg <= 0) break;
        if (nbg > nb) nbg = nb;
        feat_kernel<<<(nbg / 64) * 2, 256, 0, stream>>>(x, met, Fb, B, S, bs, nbg);
        gemm_kernel<<<nbg / 32, 256, 0, stream>>>(x, task, Wp, W2p, Fb, b1, b2,
                                                  out, B, bs, nbg);
    }
}

// Round 9
// 99.479 us; speedup vs baseline: 1.2264x; 1.2210x over previous
//
#include <hip/hip_runtime.h>
#include <hip/hip_bf16.h>

typedef short bf16x8 __attribute__((ext_vector_type(8)));
typedef float f32x4  __attribute__((ext_vector_type(4)));

#define ROWS  96              // prep row stride (80 used + 4 pbc + 12 pad, zeroed)
#define KS1   56              // f1 k-steps (K=1792; 8 s per ks)
#define KS2   6               // f2 k-steps (K=192; 8 m per ks)
#define NCOL  32              // batch columns per block

#define WP_OFF   0            // ushort [56][96][32] = 344064 B
#define W2P_OFF  344064       // ushort [6][96][32]  = 36864 B

#define E_OFF    0            // [41][16][2 ushort4] = 10496 B (col c & c+16 paired)
#define MET_OFF  10496        // int2 [448] = 3584
#define LDS_BYTES 22528       // Sum f32[176][32] aliases whole block post-loop

__device__ __forceinline__ unsigned short f2bf(float f) {
    union { float f; unsigned u; } v; v.f = f;
    unsigned r = v.u + 0x7FFFu + ((v.u >> 16) & 1u);
    return (unsigned short)(r >> 16);
}
__device__ __forceinline__ float bfl(unsigned u) {
    union { unsigned q; float f; } v; v.q = u << 16; return v.f;
}
__device__ __forceinline__ float bfh(unsigned u) {
    union { unsigned q; float f; } v; v.q = u & 0xffff0000u; return v.f;
}
__device__ __forceinline__ unsigned pk2(float a, float b) {
    __hip_bfloat162 h = __float22bfloat162_rn(make_float2(a, b));
    unsigned u; __builtin_memcpy(&u, &h, 4); return u;
}
__device__ __forceinline__ bf16x8 asbf(uint4 v) {
    union { uint4 u; bf16x8 b; } z; z.u = v; return z.b;
}

// prep (layout validated r7/r8): Wp [ks][96 rows][32 k], W2p [6][96][32].
// Row r = o*4 + p*2 + re/im; Wp rows 80-83 = pbc C rows; all else zero-padded.
// k within step: t=k&3 -> (c=t>>1 re/im, i=t&1 pol); plane j = i^p.
__global__ void prep_kernel(const float* __restrict__ W1,
                            const float* __restrict__ W2,
                            const float* __restrict__ pbcC,
                            unsigned short* __restrict__ Wp,
                            unsigned short* __restrict__ W2p, int S) {
    int idx = blockIdx.x * 256 + threadIdx.x;
    const int N1 = KS1 * ROWS * 8, N2 = KS2 * ROWS * 8;
    if (idx < N1) {
        int ks = idx / (ROWS * 8), rem = idx - ks * (ROWS * 8);
        int row = rem >> 3, kq = rem & 7;
        int s = ks * 8 + kq;
        float2 wj0 = make_float2(0.f, 0.f), wj1 = make_float2(0.f, 0.f);
        int p = 0, r = 0;
        if (s < S) {
            if (row < 80) {
                int o = row >> 2; p = (row >> 1) & 1; r = row & 1;
                wj0 = ((const float2*)W1)[(size_t)(o * 2 + 0) * S + s];
                wj1 = ((const float2*)W1)[(size_t)(o * 2 + 1) * S + s];
            } else if (row < 84) {
                p = (row >> 1) & 1; r = row & 1;
                wj0 = ((const float2*)pbcC)[s];
            }
        }
        ushort4 h; unsigned short us[4];
#pragma unroll
        for (int t = 0; t < 4; ++t) {
            int i = t & 1, cc = t >> 1, j = i ^ p;
            float2 w = j ? wj1 : wj0;
            float v = (cc == 0) ? (r ? w.y : w.x) : (r ? w.x : -w.y);
            us[t] = f2bf(v);
        }
        h.x = us[0]; h.y = us[1]; h.z = us[2]; h.w = us[3];
        ((ushort4*)Wp)[(size_t)(ks * ROWS + row) * 8 + kq] = h;
        return;
    }
    idx -= N1;
    if (idx < N2) {
        int ks = idx / (ROWS * 8), rem = idx - ks * (ROWS * 8);
        int row = rem >> 3, kq = rem & 7;
        int m = ks * 8 + kq;
        float2 wj0 = make_float2(0.f, 0.f), wj1 = make_float2(0.f, 0.f);
        int p = 0, r = 0;
        if (m < 41 && row < 80) {
            int o = row >> 2; p = (row >> 1) & 1; r = row & 1;
            wj0 = ((const float2*)W2)[(o * 2 + 0) * 41 + m];
            wj1 = ((const float2*)W2)[(o * 2 + 1) * 41 + m];
        }
        ushort4 h; unsigned short us[4];
#pragma unroll
        for (int t = 0; t < 4; ++t) {
            int i = t & 1, cc = t >> 1, j = i ^ p;
            float2 w = j ? wj1 : wj0;
            float v = (cc == 0) ? (r ? w.y : w.x) : (r ? w.x : -w.y);
            us[t] = f2bf(v);
        }
        h.x = us[0]; h.y = us[1]; h.z = us[2]; h.w = us[3];
        ((ushort4*)W2p)[(size_t)(ks * ROWS + row) * 8 + kq] = h;
    }
}

// Fused kernel: per-lane B-fragment construction — F never leaves registers.
// Block = 32 cols, 4 waves = K-quarters (14 ks each). NO barriers in K-loop.
__global__ __launch_bounds__(256, 2) void eqsonn_kernel(
    const float* __restrict__ x,            // [B,41,2,2]
    const float* __restrict__ task,         // [B,4]
    const unsigned short* __restrict__ Wp,  // [56][96][32]
    const unsigned short* __restrict__ W2p, // [6][96][32]
    const int* __restrict__ m_idx, const int* __restrict__ n_idx,
    const float* __restrict__ b1, const float* __restrict__ b2,
    float* __restrict__ out, int B, int S)
{
    __shared__ alignas(16) char ldsb[LDS_BYTES];
    const int tid  = threadIdx.x;
    const int lane = tid & 63;
    const int kh   = __builtin_amdgcn_readfirstlane(tid >> 6);
    const int l15  = lane & 15;
    const int quad = lane >> 4;
    const int b0   = blockIdx.x * NCOL;

    // ---- stage E: [k][l15][pair] — cols c and c+16 adjacent (one b128/row) ----
    for (int e = tid; e < 41 * NCOL; e += 256) {
        int bb = e / 41, k = e - bb * 41;
        int bs = b0 + bb; if (bs > B - 1) bs = B - 1;
        float4 v = ((const float4*)x)[(size_t)bs * 41 + k];
        ushort4 h;
        h.x = f2bf(v.x); h.y = f2bf(v.y); h.z = f2bf(v.z); h.w = f2bf(v.w);
        *(ushort4*)(ldsb + E_OFF + (k * 16 + (bb & 15)) * 16 + (bb >> 4) * 8) = h;
    }
    // ---- stage meta, zero-padded to 448 ----
    for (int i = tid; i < 448; i += 256) {
        int2 mm = (i < S) ? make_int2(m_idx[i], n_idx[i]) : make_int2(0, 0);
        *(int2*)(ldsb + MET_OFF + i * 8) = mm;
    }
    __syncthreads();

    f32x4 a1[6][2], a2[5][2];
#pragma unroll
    for (int i = 0; i < 6; ++i) a1[i][0] = a1[i][1] = (f32x4){0.f,0.f,0.f,0.f};
#pragma unroll
    for (int i = 0; i < 5; ++i) a2[i][0] = a2[i][1] = (f32x4){0.f,0.f,0.f,0.f};

    const unsigned short* apb = Wp + l15 * 32 + quad * 8;

    for (int ks = kh * 14; ks < kh * 14 + 14; ++ks) {
        // hoist A-frags (L2); latency covered by the F-compute below
        bf16x8 Af[6];
        const unsigned short* ap = apb + ks * (96 * 32);
#pragma unroll
        for (int mt = 0; mt < 6; ++mt) Af[mt] = *(const bf16x8*)(ap + mt * 512);

        // build B-frags for both col-groups: 2 s per lane (s = ks*8 + quad*2 + j)
        unsigned g0[4], g1[4];
        int sb = ks * 8 + quad * 2;
#pragma unroll
        for (int j = 0; j < 2; ++j) {
            int2 mm = *(const int2*)(ldsb + MET_OFF + (sb + j) * 8);
            // rows: E[20+m], E[20+m+n], E[20+n]; each b128 = col c (8B) + col c+16 (8B)
            uint4 um = *(const uint4*)(ldsb + E_OFF + ((20 + mm.x) * 16 + l15) * 16);
            uint4 ub = *(const uint4*)(ldsb + E_OFF + ((20 + mm.x + mm.y) * 16 + l15) * 16);
            uint4 un = *(const uint4*)(ldsb + E_OFF + ((20 + mm.y) * 16 + l15) * 16);
#pragma unroll
            for (int g = 0; g < 2; ++g) {
                unsigned umx = g ? um.z : um.x, umy = g ? um.w : um.y;
                unsigned ubx = g ? ub.z : ub.x, uby = g ? ub.w : ub.y;
                unsigned unx = g ? un.z : un.x, uny = g ? un.w : un.y;
                float Em0r = bfl(umx), Em0i = bfh(umx), Em1r = bfl(umy), Em1i = bfh(umy);
                float Eb0r = bfl(ubx), Eb0i = bfh(ubx), Eb1r = bfl(uby), Eb1i = bfh(uby);
                float En0r = bfl(unx), En0i = bfh(unx), En1r = bfl(uny), En1i = bfh(uny);
                float sr = Em0r * Eb0r + Em0i * Eb0i + Em1r * Eb1r + Em1i * Eb1i;
                float si = Em0i * Eb0r - Em0r * Eb0i + Em1i * Eb1r - Em1r * Eb1i;
                float F0r = sr * En0r - si * En0i, F0i = sr * En0i + si * En0r;
                float F1r = sr * En1r - si * En1i, F1i = sr * En1i + si * En1r;
                unsigned* gg = g ? g1 : g0;
                gg[j * 2 + 0] = pk2(F0r, F1r);    // k-order t: F0r,F1r,F0i,F1i
                gg[j * 2 + 1] = pk2(F0i, F1i);
            }
        }
        bf16x8 bf0 = asbf(make_uint4(g0[0], g0[1], g0[2], g0[3]));
        bf16x8 bf1 = asbf(make_uint4(g1[0], g1[1], g1[2], g1[3]));
#pragma unroll
        for (int mt = 0; mt < 6; ++mt) {
            a1[mt][0] = __builtin_amdgcn_mfma_f32_16x16x32_bf16(Af[mt], bf0, a1[mt][0], 0, 0, 0);
            a1[mt][1] = __builtin_amdgcn_mfma_f32_16x16x32_bf16(Af[mt], bf1, a1[mt][1], 0, 0, 0);
        }
    }

    // ---- f2: kh -> k2 in {kh, kh+4} (kh<2) ----
    for (int k2 = kh; k2 < 6; k2 += 4) {
        bf16x8 Af[5];
        const unsigned short* ap = W2p + k2 * (96 * 32) + l15 * 32 + quad * 8;
#pragma unroll
        for (int mt = 0; mt < 5; ++mt) Af[mt] = *(const bf16x8*)(ap + mt * 512);
        unsigned g0[4], g1[4];
        int mb = k2 * 8 + quad * 2;
#pragma unroll
        for (int j = 0; j < 2; ++j) {
            int m = mb + j;
            int mc = m < 41 ? m : 40;
            uint4 ue = *(const uint4*)(ldsb + E_OFF + (mc * 16 + l15) * 16);
            bool ok = (m < 41);
            // Ef pack: [ReE0,ReE1],[ImE0,ImE1] per m
            unsigned lo0 = ok ? ((ue.x & 0xffffu) | (ue.y << 16)) : 0u;
            unsigned hi0 = ok ? ((ue.x >> 16) | (ue.y & 0xffff0000u)) : 0u;
            unsigned lo1 = ok ? ((ue.z & 0xffffu) | (ue.w << 16)) : 0u;
            unsigned hi1 = ok ? ((ue.z >> 16) | (ue.w & 0xffff0000u)) : 0u;
            g0[j * 2] = lo0; g0[j * 2 + 1] = hi0;
            g1[j * 2] = lo1; g1[j * 2 + 1] = hi1;
        }
        bf16x8 bf0 = asbf(make_uint4(g0[0], g0[1], g0[2], g0[3]));
        bf16x8 bf1 = asbf(make_uint4(g1[0], g1[1], g1[2], g1[3]));
#pragma unroll
        for (int mt = 0; mt < 5; ++mt) {
            a2[mt][0] = __builtin_amdgcn_mfma_f32_16x16x32_bf16(Af[mt], bf0, a2[mt][0], 0, 0, 0);
            a2[mt][1] = __builtin_amdgcn_mfma_f32_16x16x32_bf16(Af[mt], bf1, a2[mt][1], 0, 0, 0);
        }
    }

    // ---- 4-phase K-reduction into Sum (aliases E/meta; E dead after this pt) ----
    __syncthreads();
    float* Sum = (float*)ldsb;   // [176][32]
#pragma unroll
    for (int ph = 0; ph < 4; ++ph) {
        if (kh == ph) {
#pragma unroll
            for (int mt = 0; mt < 6; ++mt)
#pragma unroll
                for (int g = 0; g < 2; ++g)
#pragma unroll
                    for (int reg = 0; reg < 4; ++reg) {
                        int rc = (mt * 16 + quad * 4 + reg) * 32 + g * 16 + l15;
                        if (ph == 0) Sum[rc] = a1[mt][g][reg]; else Sum[rc] += a1[mt][g][reg];
                    }
#pragma unroll
            for (int mt = 0; mt < 5; ++mt)
#pragma unroll
                for (int g = 0; g < 2; ++g)
#pragma unroll
                    for (int reg = 0; reg < 4; ++reg) {
                        int rc = (96 + mt * 16 + quad * 4 + reg) * 32 + g * 16 + l15;
                        if (ph == 0) Sum[rc] = a2[mt][g][reg]; else Sum[rc] += a2[mt][g][reg];
                    }
        }
        __syncthreads();
    }

    // ---- epilogue: wave 0, lanes 0..31 = cols ----
    if (kh == 0 && lane < NCOL) {
        int col = lane;
        float pr0 = Sum[80 * 32 + col], pi0 = Sum[81 * 32 + col];
        float pr1 = Sum[82 * 32 + col], pi1 = Sum[83 * 32 + col];
        float t0 = 0.f, t1 = 0.f, t2 = 0.f, t3 = 0.f;
#pragma unroll
        for (int o = 0; o < 10; ++o) {
            float b2r = b2[o * 2], b2i = b2[o * 2 + 1];
            float b1r = b1[o * 2], b1i = b1[o * 2 + 1];
            int rb = o * 4;
            float B0r = Sum[(96 + rb + 0) * 32 + col] + b2r;
            float B0i = Sum[(96 + rb + 1) * 32 + col] + b2i;
            float B1r = Sum[(96 + rb + 2) * 32 + col] + b2r;
            float B1i = Sum[(96 + rb + 3) * 32 + col] + b2i;
            float A0r = Sum[(rb + 0) * 32 + col] + b1r;
            float A0i = Sum[(rb + 1) * 32 + col] + b1i;
            float A1r = Sum[(rb + 2) * 32 + col] + b1r;
            float A1i = Sum[(rb + 3) * 32 + col] + b1i;
            // A*B*conj(B) + conj(A)*B*B = 2*Re(A*conj(B)) * B
            float g0 = 2.f * (A0r * B0r + A0i * B0i);
            t0 += g0 * B0r; t1 += g0 * B0i;
            float g1 = 2.f * (A1r * B1r + A1i * B1i);
            t2 += g1 * B1r; t3 += g1 * B1i;
        }
        int b = b0 + col;
        if (b < B) {
            float dbm = task[(size_t)b * 4];
            float P   = exp2f(dbm * 0.33219280948873623f) * 0.5f;  // 10^(dbm/10)/2
            float kP2 = 3.1622776601683794e-05f * P * P;           // 1e-4/sqrt(10)*P^2
            float4 Ec = ((const float4*)x)[(size_t)b * 41 + 20];   // fp32 center symbol
            float4 o4;
            o4.x = Ec.x + P * pr0 + kP2 * t0;
            o4.y = Ec.y + P * pi0 + kP2 * t1;
            o4.z = Ec.z + P * pr1 + kP2 * t2;
            o4.w = Ec.w + P * pi1 + kP2 * t3;
            ((float4*)out)[b] = o4;
        }
    }
}

extern "C" void kernel_launch(void* const* d_in, const int* in_sizes, int n_in,
                              void* d_out, int out_size, void* d_ws, size_t ws_size,
                              hipStream_t stream) {
    const float* x     = (const float*)d_in[0];
    const float* task  = (const float*)d_in[1];
    const float* pbcC  = (const float*)d_in[2];
    const float* W1    = (const float*)d_in[3];
    const float* b1    = (const float*)d_in[4];
    const float* W2    = (const float*)d_in[5];
    const float* b2    = (const float*)d_in[6];
    const int*   m_idx = (const int*)d_in[7];
    const int*   n_idx = (const int*)d_in[8];
    float* out = (float*)d_out;

    int S = in_sizes[7];
    int B = in_sizes[0] / (41 * 2 * 2);

    char* ws = (char*)d_ws;
    unsigned short* Wp  = (unsigned short*)(ws + WP_OFF);
    unsigned short* W2p = (unsigned short*)(ws + W2P_OFF);

    int prep_n = KS1 * ROWS * 8 + KS2 * ROWS * 8;
    prep_kernel<<<(prep_n + 255) / 256, 256, 0, stream>>>(W1, W2, pbcC, Wp, W2p, S);

    int grid = (B + NCOL - 1) / NCOL;
    eqsonn_kernel<<<grid, 256, 0, stream>>>(x, task, Wp, W2p, m_idx, n_idx,
                                            b1, b2, out, B, S);
}